// Round 16
// baseline (898.068 us; speedup 1.0000x reference)
//
#include <hip/hip_runtime.h>
#include <hip/hip_bf16.h>

#define Hn   89
#define Tn   120
#define BM   128
#define HPB  208                 // h bf16 pitch bytes (104 cols)
#define HPLANE (BM*HPB)          // 26,624 B
#define ROWB (Tn*Hn*4)           // 42,720 B per batch row
#define TSTEP (Hn*4)             // 356

#define SRZ (-1.44269504f)       // sigmoid pre-scale folded into r/z weights
#define SNN ( 2.88539008f)       // tanh pre-scale folded into n weights

using bf16   = __bf16;
using bf16x4 = __attribute__((ext_vector_type(4))) __bf16;
using bf16x8 = __attribute__((ext_vector_type(8))) __bf16;
typedef __attribute__((ext_vector_type(4))) float f32x4;

__device__ __forceinline__ f32x4 ld4(const void* p) {   // 4B-aligned 16B load
  f32x4 v; __builtin_memcpy(&v, p, 16); return v;
}
__device__ __forceinline__ bf16x8 pack8(f32x4 a, f32x4 b) {
  bf16x8 r;
  r[0]=(bf16)a[0]; r[1]=(bf16)a[1]; r[2]=(bf16)a[2]; r[3]=(bf16)a[3];
  r[4]=(bf16)b[0]; r[5]=(bf16)b[1]; r[6]=(bf16)b[2]; r[7]=(bf16)b[3];
  return r;
}
__device__ __forceinline__ float frcp(float x) { return __builtin_amdgcn_rcpf(x); }
__device__ __forceinline__ float fex2(float x) { return __builtin_amdgcn_exp2f(x); }
__device__ __forceinline__ float fsig(float x) { return frcp(1.f + fex2(-1.44269504f * x)); }

// X-direct variant of the r8 champion (r15 + the jt==5 mask fix: r15 tested
// wv==5, which is (jt=2,hf=1) in the 12-wave map — it stomped j=41..47 for
// rows 64..127 and left h[89] at 0, killing all hh-side biases).
// X B-frags load straight from global (L1/L2-served); LDS holds ONLY h.
// X k-windows {0-31, 32-63, 57-88}: the third is shifted to end exactly at
// the row boundary (no OOB, no patching); the 57..63 overlap is zeroed in
// the kt2 weights. Biases: r/z sums and bhn ride the h[89]==1.0 column
// (Whh k=89); bin is a register fma (binq). 12 waves = 6 j-slices x 2 row
// halves; swapped-operand MFMA; h carried in LDS only; one barrier/step.
__global__ __launch_bounds__(768, 3)
void gru_fused(const float* __restrict__ X,    // [B][T][89]
               const float* __restrict__ Wih,  // [267][89]
               const float* __restrict__ Whh,  // [267][89]
               const float* __restrict__ bih,  // [267]
               const float* __restrict__ bhh,  // [267]
               const float* __restrict__ Wm,   // [32][89]
               const float* __restrict__ bm,   // [32]
               const float* __restrict__ Wo,   // [32]
               const float* __restrict__ bo,   // [1]
               float* __restrict__ Y,          // [B] mscore | [B][32] mmetric
               int Bt)
{
  __shared__ __align__(16) char hraw[2 * HPLANE];   // 53,248 B

  const int tid  = threadIdx.x;
  const int lane = tid & 63;
  const int wv   = tid >> 6;       // 0..11
  const int jt   = wv >> 1;        // j-slice 0..5
  const int hf   = wv & 1;         // row half
  const int l15  = lane & 15;
  const int kg   = lane >> 4;      // 0..3
  const size_t brow0 = (size_t)blockIdx.x * BM;
  const char* xgw = (const char*)(X + brow0 * (size_t)(Tn * Hn));

  // ---- weights -> 18 persistent A-frags (72 VGPR); pre-scaled ----
  const int jA = jt * 16 + l15;
  const bool jAok = (jA < Hn);
  bf16x8 Bf[3][2][3];  // [gate r/z/n][ih/hh][k-tile]
#pragma unroll
  for (int g = 0; g < 3; ++g)
#pragma unroll
    for (int s = 0; s < 2; ++s) {
      const float sc = (g < 2) ? SRZ : SNN;
#pragma unroll
      for (int kt = 0; kt < 3; ++kt) {
        bf16x8 f;
#pragma unroll
        for (int e = 0; e < 8; ++e) {
          float v = 0.f;
          if (jAok) {
            if (s == 0) {        // ih side: k-windows {0..31, 32..63, 57..88}
              const int k = (kt < 2) ? kt * 32 + kg * 8 + e : 57 + kg * 8 + e;
              if (kt < 2 || k >= 64)   // zero the 57..63 overlap in kt2
                v = sc * Wih[(size_t)(g * Hn + jA) * Hn + k];
            } else {             // hh side: k-windows {0..31, 32..63, 64..95}
              const int k = kt * 32 + kg * 8 + e;
              if (k < Hn)       v = sc * Whh[(size_t)(g * Hn + jA) * Hn + k];
              else if (k == Hn) // bias column, pairs with h[89]==1.0
                v = (g < 2) ? sc * (bih[g * Hn + jA] + bhh[g * Hn + jA])
                            : SNN * bhh[2 * Hn + jA];
            }
          }
          f[e] = (bf16)v;
        }
        Bf[g][s][kt] = f;
      }
    }

  float binq[4];
#pragma unroll
  for (int q = 0; q < 4; ++q) {
    const int j = jt * 16 + kg * 4 + q;
    binq[q] = (j < Hn) ? SNN * bih[2 * Hn + j] : 0.f;
  }

  // ---- lane-constant addressing ----
  unsigned rb[4];                          // global row bases (this wave's rows)
#pragma unroll
  for (int mt = 0; mt < 4; ++mt)
    rb[mt] = (unsigned)((hf * 64 + mt * 16 + l15) * ROWB);
  const unsigned ko[3] = { (unsigned)(kg * 32),
                           (unsigned)(128 + kg * 32),
                           (unsigned)(228 + kg * 32) };   // k-window byte offs
  const unsigned hro = (unsigned)((hf * 64 + l15) * HPB + kg * 16);       // frags
  const unsigned hco = (unsigned)((hf * 64 + l15) * HPB + (jt * 16 + kg * 4) * 2); // C/D

  // ---- prologue: h(0) = 0 -> plane 0 (h[89]=1.0 bias col via jt5/kg2) ----
  {
    bf16x4 z4 = {(bf16)0.f, (bf16)0.f, (bf16)0.f, (bf16)0.f};
    if (jt == 5 && kg == 2) z4[1] = (bf16)1.0f;       // FIX: jt==5, not wv==5
#pragma unroll
    for (int mt = 0; mt < 4; ++mt)
      *(bf16x4*)(hraw + hco + mt * 16 * HPB) = z4;
  }

  for (int t = 0; t < Tn; ++t) {
    const int b = t & 1;
    __syncthreads();                       // plane b holds h(t)
    const char* hrp = hraw + b * HPLANE;
    char*       hwp = hraw + (b ^ 1) * HPLANE;
    const unsigned xb = (unsigned)t * (unsigned)TSTEP;

    __builtin_amdgcn_s_setprio(1);
#pragma unroll
    for (int mt = 0; mt < 4; ++mt) {
      // X B-frags straight from global (L1/L2-hot; rows shared by 6 jt-waves)
      bf16x8 xf[3], hfr[3];
#pragma unroll
      for (int kt = 0; kt < 3; ++kt) {
        const char* pa = xgw + (rb[mt] + xb + ko[kt]);
        xf[kt]  = pack8(ld4(pa), ld4(pa + 16));
        hfr[kt] = *(const bf16x8*)(hrp + hro + mt * 16 * HPB + kt * 64);
      }
      f32x4 ar = {0,0,0,0}, az = {0,0,0,0}, ain = {0,0,0,0}, ahn = {0,0,0,0};
#pragma unroll
      for (int kt = 0; kt < 3; ++kt) {
        ar  = __builtin_amdgcn_mfma_f32_16x16x32_bf16(Bf[0][0][kt], xf[kt],  ar, 0, 0, 0);
        ar  = __builtin_amdgcn_mfma_f32_16x16x32_bf16(Bf[0][1][kt], hfr[kt], ar, 0, 0, 0);
        az  = __builtin_amdgcn_mfma_f32_16x16x32_bf16(Bf[1][0][kt], xf[kt],  az, 0, 0, 0);
        az  = __builtin_amdgcn_mfma_f32_16x16x32_bf16(Bf[1][1][kt], hfr[kt], az, 0, 0, 0);
        ain = __builtin_amdgcn_mfma_f32_16x16x32_bf16(Bf[2][0][kt], xf[kt],  ain, 0, 0, 0);
        ahn = __builtin_amdgcn_mfma_f32_16x16x32_bf16(Bf[2][1][kt], hfr[kt], ahn, 0, 0, 0);
      }
      const bf16x4 hp4 = *(const bf16x4*)(hrp + hco + mt * 16 * HPB);
      bf16x4 wv4;
#pragma unroll
      for (int q = 0; q < 4; ++q) {
        const float r_ = frcp(1.f + fex2(ar[q]));
        const float z_ = frcp(1.f + fex2(az[q]));
        const float s_ = ain[q] + binq[q] + r_ * ahn[q];   // ahn includes bhn
        const float n_ = fmaf(-2.f, frcp(1.f + fex2(s_)), 1.f);
        const float hv = n_ + z_ * ((float)hp4[q] - n_);
        wv4[q] = (bf16)hv;
      }
      if (jt == 5) {   // FIX: jt==5 (j=80+4kg+q): col89=1.0, cols>=90 -> 0
        if (kg == 2) { wv4[1] = (bf16)1.0f; wv4[2] = (bf16)0.f; wv4[3] = (bf16)0.f; }
        if (kg == 3) { wv4[0] = (bf16)0.f; wv4[1] = (bf16)0.f;
                       wv4[2] = (bf16)0.f; wv4[3] = (bf16)0.f; }
      }
      *(bf16x4*)(hwp + hco + mt * 16 * HPB) = wv4;   // h(t+1), aligned b64
    }
    __builtin_amdgcn_s_setprio(0);
  }
  __syncthreads();   // h(120) in plane 0

  // ---- epilogue: metric_fc (89->32, sigmoid), output_fc (32->1, sigmoid) ----
  char* const mlb = hraw + HPLANE;         // reuse plane 1: [128][32] f32
  for (int p = tid; p < BM * 32; p += 768) {
    const int r = p >> 5, c = p & 31;
    const char* hr2 = hraw + r * HPB;
    const float* wrow = Wm + c * Hn;
    float acc = bm[c];
#pragma unroll 4
    for (int cbk = 0; cbk < 11; ++cbk) {
      const bf16x8 hv = *(const bf16x8*)(hr2 + cbk * 16);
      const f32x4 wa = ld4(wrow + cbk * 8);
      const f32x4 wb = ld4(wrow + cbk * 8 + 4);
      acc = fmaf((float)hv[0], wa[0], acc); acc = fmaf((float)hv[1], wa[1], acc);
      acc = fmaf((float)hv[2], wa[2], acc); acc = fmaf((float)hv[3], wa[3], acc);
      acc = fmaf((float)hv[4], wb[0], acc); acc = fmaf((float)hv[5], wb[1], acc);
      acc = fmaf((float)hv[6], wb[2], acc); acc = fmaf((float)hv[7], wb[3], acc);
    }
    acc = fmaf((float)*(const bf16*)(hr2 + 176), wrow[88], acc);   // k=88
    const float mv = fsig(acc);
    *(float*)(mlb + r * 128 + c * 4) = mv;
    Y[(size_t)Bt + (brow0 + r) * 32 + c] = mv;   // out_mmetric
  }
  __syncthreads();
  if (tid < BM) {
    float acc = bo[0];
#pragma unroll
    for (int c = 0; c < 32; ++c)
      acc = fmaf(*(const float*)(mlb + tid * 128 + c * 4), Wo[c], acc);
    Y[brow0 + tid] = fsig(acc);                  // out_mscore
  }
}

extern "C" void kernel_launch(void* const* d_in, const int* in_sizes, int n_in,
                              void* d_out, int out_size, void* d_ws, size_t ws_size,
                              hipStream_t stream) {
  const float* X   = (const float*)d_in[0];
  const float* Wih = (const float*)d_in[1];
  const float* Whh = (const float*)d_in[2];
  const float* bih = (const float*)d_in[3];
  const float* bhh = (const float*)d_in[4];
  const float* Wm  = (const float*)d_in[5];
  const float* bm  = (const float*)d_in[6];
  const float* Wo  = (const float*)d_in[7];
  const float* bo  = (const float*)d_in[8];

  const int B = in_sizes[0] / (Tn * Hn);   // 32768
  dim3 grid(B / BM), block(768);
  gru_fused<<<grid, block, 0, stream>>>(X, Wih, Whh, bih, bhh, Wm, bm, Wo, bo,
                                        (float*)d_out, B);
}